// Round 10
// baseline (269.753 us; speedup 1.0000x reference)
//
#include <hip/hip_runtime.h>
#include <math.h>
#include <stdint.h>

#define N_SAMPLES 1000000
#define NBITS 48
#define CHUNK 4096
#define NB ((N_SAMPLES + CHUNK - 1) / CHUNK)      // 245 sort blocks
#define GBLK ((N_SAMPLES + 255) / 256)            // 3907 generic blocks

typedef unsigned int u32;
typedef unsigned long long u64;

// ---- XLA CPU fast-tanh (Eigen rational, FMA), used by logistic expansion --
__device__ __forceinline__ float xla_tanh_f32(float x) {
    float ax = fabsf(x);
    float cx = fminf(fmaxf(x, -9.0f), 9.0f);
    float x2 = cx * cx;
    float p = fmaf(x2, -2.76076847742355e-16f, 2.00018790482477e-13f); // a13,a11
    p = fmaf(x2, p, -8.60467152213735e-11f);   // a9
    p = fmaf(x2, p, 5.12229709037114e-08f);    // a7
    p = fmaf(x2, p, 1.48572235717979e-05f);    // a5
    p = fmaf(x2, p, 6.37261928875436e-04f);    // a3
    p = fmaf(x2, p, 4.89352455891786e-03f);    // a1
    p = cx * p;
    float q = fmaf(x2, 1.19825839466702e-06f, 1.18534705686654e-04f);  // b6,b4
    q = fmaf(x2, q, 2.26843463243900e-03f);    // b2
    q = fmaf(x2, q, 4.89352518554385e-03f);    // b0
    float r = p / q;
    return (ax < 0.0004f) ? x : r;
}

// ---- pack + inline probs + pass-0 histogram (transposed g_hist[b][d]) -----
__global__ void pack_hist0_kernel(const float* __restrict__ theta, const float* __restrict__ u,
                                  u32* __restrict__ keys, int* __restrict__ g_hist) {
    __shared__ float sp[32];
    __shared__ int h[256];
    int tid = threadIdx.x, b = blockIdx.x;
    if (tid < 32) sp[tid] = 0.5f + 0.5f * xla_tanh_f32(theta[tid]);
    if (tid < 256) h[tid] = 0;
    __syncthreads();
    int base = b * CHUNK;
#pragma unroll
    for (int k2 = 0; k2 < 8; ++k2) {
        int i = base + k2 * 512 + tid;
        if (i < N_SAMPLES) {
            const float4* row = (const float4*)(u + (size_t)i * NBITS);
            u32 key = 0u;
#pragma unroll
            for (int q = 0; q < 8; ++q) {
                float4 v = row[q];
                int j = q * 4;
                key |= ((u32)(v.x < sp[j + 0])) << (j + 0);
                key |= ((u32)(v.y < sp[j + 1])) << (j + 1);
                key |= ((u32)(v.z < sp[j + 2])) << (j + 2);
                key |= ((u32)(v.w < sp[j + 3])) << (j + 3);
            }
            key ^= 0x80000000u;
            keys[i] = key;
            atomicAdd(&h[key & 255u], 1);
        }
    }
    __syncthreads();
    if (tid < 256) g_hist[b * 256 + tid] = h[tid];
}

// ---- per-pass histogram (passes 1..3), transposed write -------------------
__global__ void hist_kernel(const u32* __restrict__ keys, int shift, int* __restrict__ g_hist) {
    __shared__ int h[256];
    int tid = threadIdx.x, b = blockIdx.x;
    h[tid] = 0;
    __syncthreads();
    int base = b * CHUNK;
#pragma unroll
    for (int k = 0; k < CHUNK / 256; ++k) {
        int idx = base + k * 256 + tid;
        if (idx < N_SAMPLES) {
            int d = (int)((keys[idx] >> shift) & 255u);
            atomicAdd(&h[d], 1);
        }
    }
    __syncthreads();
    g_hist[b * 256 + tid] = h[tid];
}

// ---- stable scatter: 512 threads (8 waves), self-served offsets -----------
// Each block computes its own per-digit prefix (sum over earlier blocks) and
// digitTotal from the transposed g_hist, then dbase via local 256-scan.
// Stability: lane rank (ballot) within wave; wave order via LDS prefix
// (wave order == element order); groups sequential via counter.
__global__ void scatter_kernel(const u32* __restrict__ keysIn, u32* __restrict__ keysOut,
                               const int* __restrict__ g_hist, int shift) {
    __shared__ int counter[256];
    __shared__ int s[256];
    __shared__ int ws_cnt[8][256];
    __shared__ int ws_base[8][256];
    int tid = threadIdx.x, b = blockIdx.x;
    int lane = tid & 63, w = tid >> 6;

    // Phase A: per-digit prefix over earlier blocks + total (threads 0..255)
    int pre = 0, tot = 0;
    if (tid < 256) {
#pragma unroll 4
        for (int bp = 0; bp < NB; ++bp) {
            int v = g_hist[bp * 256 + tid];
            if (bp < b) pre += v;
            tot += v;
        }
        s[tid] = tot;
    }
#pragma unroll
    for (int wv = 0; wv < 8; ++wv) { ws_cnt[wv][tid & 255] = 0; }
    __syncthreads();
    // Phase B: exclusive scan of totals -> dbase, then counter
    if (tid < 256) {
        int v = s[tid];
        for (int o = 1; o < 256; o <<= 1) {
            int x = (tid >= o) ? s[tid - o] : 0;
            __syncthreads();
            s[tid] += x;
            __syncthreads();
        }
        counter[tid] = (s[tid] - v) + pre;   // dbase + block prefix
    } else {
        for (int o = 1; o < 256; o <<= 1) { __syncthreads(); __syncthreads(); }
    }
    __syncthreads();

    int base = b * CHUNK;
#pragma unroll
    for (int it = 0; it < CHUNK / 512; ++it) {
        int idx = base + it * 512 + tid;
        bool valid = idx < N_SAMPLES;
        u32 key = valid ? keysIn[idx] : 0u;
        int dig = (int)((key >> shift) & 255u);
        u64 mask = __ballot(valid);
#pragma unroll
        for (int bit = 0; bit < 8; ++bit) {
            u64 bb = __ballot((dig >> bit) & 1);
            mask &= ((dig >> bit) & 1) ? bb : ~bb;
        }
        u64 below = mask & ((1ull << lane) - 1ull);
        int rank = __popcll(below);
        if (valid && below == 0ull) ws_cnt[w][dig] = __popcll(mask);
        __syncthreads();
        if (tid < 256) {   // per-digit cross-wave prefix + counter + reset
            int d = tid;
            int cb = counter[d];
#pragma unroll
            for (int wv = 0; wv < 8; ++wv) {
                int c = ws_cnt[wv][d];
                ws_base[wv][d] = cb;
                cb += c;
                ws_cnt[wv][d] = 0;
            }
            counter[d] = cb;
        }
        __syncthreads();
        if (valid) keysOut[ws_base[w][dig] + rank] = key;
    }
}

// ---- unique: head flags -> block sums -------------------------------------
__global__ void head_reduce_kernel(const u32* __restrict__ keys, int* __restrict__ blockSums) {
    __shared__ int s[256];
    int tid = threadIdx.x;
    int i = blockIdx.x * 256 + tid;
    int h = 0;
    if (i < N_SAMPLES) h = (i == 0) || (keys[i] != keys[i - 1]);
    s[tid] = h;
    __syncthreads();
    for (int o = 128; o > 0; o >>= 1) {
        if (tid < o) s[tid] += s[tid + o];
        __syncthreads();
    }
    if (tid == 0) blockSums[blockIdx.x] = s[0];
}

__global__ void block_scan_kernel(const int* __restrict__ blockSums, int* __restrict__ blockOffs,
                                  int* __restrict__ dU) {
    __shared__ int s[1024];
    int t = threadIdx.x;
    const int PER = 4;                    // ceil(3907/1024)
    int base = t * PER;
    int v[PER];
    int sum = 0;
#pragma unroll
    for (int k = 0; k < PER; ++k) {
        int idx = base + k;
        v[k] = (idx < GBLK) ? blockSums[idx] : 0;
        sum += v[k];
    }
    s[t] = sum;
    __syncthreads();
    for (int o = 1; o < 1024; o <<= 1) {
        int x = (t >= o) ? s[t - o] : 0;
        __syncthreads();
        s[t] += x;
        __syncthreads();
    }
    int run = s[t] - sum;
#pragma unroll
    for (int k = 0; k < PER; ++k) {
        int idx = base + k;
        if (idx < GBLK) blockOffs[idx] = run;
        run += v[k];
    }
    if (t == 1023) *dU = s[1023];
}

__global__ void compact_kernel(const u32* __restrict__ keys, const int* __restrict__ blockOffs,
                               u32* __restrict__ uniqKey, int* __restrict__ headPos,
                               const int* __restrict__ dU) {
    __shared__ int s[256];
    int tid = threadIdx.x;
    int i = blockIdx.x * 256 + tid;
    int h = 0;
    u32 key = 0u;
    if (i < N_SAMPLES) {
        key = keys[i];
        h = (i == 0) || (key != keys[i - 1]);
    }
    s[tid] = h;
    __syncthreads();
    for (int o = 1; o < 256; o <<= 1) {
        int x = (tid >= o) ? s[tid - o] : 0;
        __syncthreads();
        s[tid] += x;
        __syncthreads();
    }
    int excl = s[tid] - h;
    if (h) {
        int j = blockOffs[blockIdx.x] + excl;
        uniqKey[j] = key;
        headPos[j] = i;
    }
    if (i == 0) headPos[*dU] = N_SAMPLES;
}

// ---- fill: unpack 32-bit key to cols 0..31, zeros 32..47, counts int32 ----
__global__ void fill_kernel(const u32* __restrict__ uniqKey, const int* __restrict__ headPos,
                            const int* __restrict__ dU, int* __restrict__ out) {
    int j = blockIdx.x * 256 + threadIdx.x;
    if (j >= N_SAMPLES) return;
    int U = *dU;
    int4* bits = (int4*)out + (size_t)j * 12;
    int cnt = 0;
    if (j < U) {
        u32 k = uniqKey[j] ^ 0x80000000u;   // undo signed-order transform
#pragma unroll
        for (int q = 0; q < 8; ++q) {
            int c = q * 4;
            int4 v;
            v.x = (int)((k >> (c + 0)) & 1u);
            v.y = (int)((k >> (c + 1)) & 1u);
            v.z = (int)((k >> (c + 2)) & 1u);
            v.w = (int)((k >> (c + 3)) & 1u);
            bits[q] = v;
        }
        int4 z = make_int4(0, 0, 0, 0);
#pragma unroll
        for (int q = 8; q < 12; ++q) bits[q] = z;   // cols 32..47
        cnt = headPos[j + 1] - headPos[j];
    } else {
        int4 z = make_int4(0, 0, 0, 0);
#pragma unroll
        for (int q = 0; q < 12; ++q) bits[q] = z;
    }
    out[(size_t)N_SAMPLES * NBITS + j] = cnt;
}

extern "C" void kernel_launch(void* const* d_in, const int* in_sizes, int n_in,
                              void* d_out, int out_size, void* d_ws, size_t ws_size,
                              hipStream_t stream) {
    const float* theta = (const float*)d_in[0];
    const float* u = (const float*)d_in[1];
    int* out = (int*)d_out;
    char* ws = (char*)d_ws;

    u32* keysA = (u32*)(ws + 0);                 // 4,000,000 B
    u32* keysB = (u32*)(ws + 4000000);           // 4,000,000 B (later uniqKey)
    int* headPos = (int*)(ws + 8000000);         // 4,000,004 B
    int* g_hist = (int*)(ws + 12000256);         // 245*256*4 = 250,880 B
    int* blockSums = (int*)(ws + 12600000);      // 15,628 B
    int* blockOffs = (int*)(ws + 12700032);      // 15,628 B
    int* dU = (int*)(ws + 12800000);             // 4 B

    // pass 0: pack + hist fused; scatter self-serves offsets from g_hist
    pack_hist0_kernel<<<NB, 512, 0, stream>>>(theta, u, keysA, g_hist);
    scatter_kernel<<<NB, 512, 0, stream>>>(keysA, keysB, g_hist, 0);

    u32* kin = keysB;
    u32* kout = keysA;
    for (int pass = 1; pass < 4; ++pass) {
        int shift = pass * 8;
        hist_kernel<<<NB, 256, 0, stream>>>(kin, shift, g_hist);
        scatter_kernel<<<NB, 512, 0, stream>>>(kin, kout, g_hist, shift);
        u32* t = kin; kin = kout; kout = t;
    }
    // 4 passes total -> sorted keys in keysA (kin == keysA), keysB free
    u32* uniqKey = keysB;

    head_reduce_kernel<<<GBLK, 256, 0, stream>>>(kin, blockSums);
    block_scan_kernel<<<1, 1024, 0, stream>>>(blockSums, blockOffs, dU);
    compact_kernel<<<GBLK, 256, 0, stream>>>(kin, blockOffs, uniqKey, headPos, dU);
    fill_kernel<<<GBLK, 256, 0, stream>>>(uniqKey, headPos, dU, out);
}

// Round 11
// 195.631 us; speedup vs baseline: 1.3789x; 1.3789x over previous
//
#include <hip/hip_runtime.h>
#include <math.h>
#include <stdint.h>

#define N_SAMPLES 1000000
#define NBITS 48
#define CHUNK 2048
#define NB ((N_SAMPLES + CHUNK - 1) / CHUNK)      // 489 sort blocks
#define GBLK ((N_SAMPLES + 255) / 256)            // 3907 generic blocks

typedef unsigned int u32;
typedef unsigned long long u64;

// ---- XLA CPU fast-tanh (Eigen rational, FMA), used by logistic expansion --
__device__ __forceinline__ float xla_tanh_f32(float x) {
    float ax = fabsf(x);
    float cx = fminf(fmaxf(x, -9.0f), 9.0f);
    float x2 = cx * cx;
    float p = fmaf(x2, -2.76076847742355e-16f, 2.00018790482477e-13f); // a13,a11
    p = fmaf(x2, p, -8.60467152213735e-11f);   // a9
    p = fmaf(x2, p, 5.12229709037114e-08f);    // a7
    p = fmaf(x2, p, 1.48572235717979e-05f);    // a5
    p = fmaf(x2, p, 6.37261928875436e-04f);    // a3
    p = fmaf(x2, p, 4.89352455891786e-03f);    // a1
    p = cx * p;
    float q = fmaf(x2, 1.19825839466702e-06f, 1.18534705686654e-04f);  // b6,b4
    q = fmaf(x2, q, 2.26843463243900e-03f);    // b2
    q = fmaf(x2, q, 4.89352518554385e-03f);    // b0
    float r = p / q;
    return (ax < 0.0004f) ? x : r;
}

// ---- pack + inline probs + pass-0 histogram (NO fences, NO flags) ---------
__global__ void pack_hist0_kernel(const float* __restrict__ theta, const float* __restrict__ u,
                                  u32* __restrict__ keys, int* __restrict__ g_hist) {
    __shared__ float sp[32];
    __shared__ int h[256];
    int tid = threadIdx.x, b = blockIdx.x;
    if (tid < 32) sp[tid] = 0.5f + 0.5f * xla_tanh_f32(theta[tid]);
    h[tid] = 0;
    __syncthreads();
    int base = b * CHUNK;
#pragma unroll
    for (int k2 = 0; k2 < 8; ++k2) {
        int i = base + k2 * 256 + tid;
        if (i < N_SAMPLES) {
            const float4* row = (const float4*)(u + (size_t)i * NBITS);
            u32 key = 0u;
#pragma unroll
            for (int q = 0; q < 8; ++q) {
                float4 v = row[q];
                int j = q * 4;
                key |= ((u32)(v.x < sp[j + 0])) << (j + 0);
                key |= ((u32)(v.y < sp[j + 1])) << (j + 1);
                key |= ((u32)(v.z < sp[j + 2])) << (j + 2);
                key |= ((u32)(v.w < sp[j + 3])) << (j + 3);
            }
            key ^= 0x80000000u;
            keys[i] = key;
            atomicAdd(&h[key & 255u], 1);
        }
    }
    __syncthreads();
    g_hist[tid * NB + b] = h[tid];
}

// ---- per-pass histogram (passes 1..3) -------------------------------------
__global__ void hist_kernel(const u32* __restrict__ keys, int shift, int* __restrict__ g_hist) {
    __shared__ int h[256];
    int tid = threadIdx.x, b = blockIdx.x;
    h[tid] = 0;
    __syncthreads();
    int base = b * CHUNK;
#pragma unroll
    for (int k = 0; k < CHUNK / 256; ++k) {
        int idx = base + k * 256 + tid;
        if (idx < N_SAMPLES) {
            int d = (int)((keys[idx] >> shift) & 255u);
            atomicAdd(&h[d], 1);
        }
    }
    __syncthreads();
    g_hist[tid * NB + b] = h[tid];
}

// ---- per-digit cross-block scan (g_off) + per-digit totals ----------------
__global__ void scan_digit_kernel(const int* __restrict__ g_hist, int* __restrict__ g_off,
                                  int* __restrict__ digitTotal) {
    __shared__ int s[512];
    int t = threadIdx.x, d = blockIdx.x;
    int v = (t < NB) ? g_hist[d * NB + t] : 0;
    s[t] = v;
    __syncthreads();
    for (int o = 1; o < 512; o <<= 1) {
        int x = (t >= o) ? s[t - o] : 0;
        __syncthreads();
        s[t] += x;
        __syncthreads();
    }
    if (t < NB) g_off[d * NB + t] = s[t] - v;
    if (t == 511) digitTotal[d] = s[511];
}

// ---- stable scatter: 512 threads (8 waves), local digitBase recompute -----
// Stability: within wave by lane (ballot rank); across waves by LDS 8-step
// prefix (wave order == element order in each 512-element group); across
// groups by sequential counter accumulation.
__global__ void scatter_kernel(const u32* __restrict__ keysIn, u32* __restrict__ keysOut,
                               const int* __restrict__ g_off, const int* __restrict__ digitTotal,
                               int shift) {
    __shared__ int counter[256];
    __shared__ int s[256];
    __shared__ int ws_cnt[8][256];
    __shared__ int ws_base[8][256];
    int tid = threadIdx.x, b = blockIdx.x;
    int lane = tid & 63, w = tid >> 6;

    // local exclusive scan of digitTotal -> dbase; counter = dbase + g_off
    int v = 0;
    if (tid < 256) { v = digitTotal[tid]; s[tid] = v; }
#pragma unroll
    for (int wv = 0; wv < 8; ++wv) ws_cnt[wv][tid & 255] = 0;
    __syncthreads();
    for (int o = 1; o < 256; o <<= 1) {
        int x = 0;
        if (tid < 256 && tid >= o) x = s[tid - o];
        __syncthreads();
        if (tid < 256) s[tid] += x;
        __syncthreads();
    }
    if (tid < 256) counter[tid] = (s[tid] - v) + g_off[tid * NB + b];
    __syncthreads();

    int base = b * CHUNK;
#pragma unroll
    for (int it = 0; it < CHUNK / 512; ++it) {
        int idx = base + it * 512 + tid;
        bool valid = idx < N_SAMPLES;
        u32 key = valid ? keysIn[idx] : 0u;
        int dig = (int)((key >> shift) & 255u);
        u64 mask = __ballot(valid);
#pragma unroll
        for (int bit = 0; bit < 8; ++bit) {
            u64 bb = __ballot((dig >> bit) & 1);
            mask &= ((dig >> bit) & 1) ? bb : ~bb;
        }
        u64 below = mask & ((1ull << lane) - 1ull);
        int rank = __popcll(below);
        if (valid && below == 0ull) ws_cnt[w][dig] = __popcll(mask);
        __syncthreads();
        if (tid < 256) {   // per-digit cross-wave prefix + counter + reset
            int d = tid;
            int cb = counter[d];
#pragma unroll
            for (int wv = 0; wv < 8; ++wv) {
                int c = ws_cnt[wv][d];
                ws_base[wv][d] = cb;
                cb += c;
                ws_cnt[wv][d] = 0;
            }
            counter[d] = cb;
        }
        __syncthreads();
        if (valid) keysOut[ws_base[w][dig] + rank] = key;
    }
}

// ---- unique: head flags -> block sums -------------------------------------
__global__ void head_reduce_kernel(const u32* __restrict__ keys, int* __restrict__ blockSums) {
    __shared__ int s[256];
    int tid = threadIdx.x;
    int i = blockIdx.x * 256 + tid;
    int h = 0;
    if (i < N_SAMPLES) h = (i == 0) || (keys[i] != keys[i - 1]);
    s[tid] = h;
    __syncthreads();
    for (int o = 128; o > 0; o >>= 1) {
        if (tid < o) s[tid] += s[tid + o];
        __syncthreads();
    }
    if (tid == 0) blockSums[blockIdx.x] = s[0];
}

__global__ void block_scan_kernel(const int* __restrict__ blockSums, int* __restrict__ blockOffs,
                                  int* __restrict__ dU) {
    __shared__ int s[1024];
    int t = threadIdx.x;
    const int PER = 4;                    // ceil(3907/1024)
    int base = t * PER;
    int v[PER];
    int sum = 0;
#pragma unroll
    for (int k = 0; k < PER; ++k) {
        int idx = base + k;
        v[k] = (idx < GBLK) ? blockSums[idx] : 0;
        sum += v[k];
    }
    s[t] = sum;
    __syncthreads();
    for (int o = 1; o < 1024; o <<= 1) {
        int x = (t >= o) ? s[t - o] : 0;
        __syncthreads();
        s[t] += x;
        __syncthreads();
    }
    int run = s[t] - sum;
#pragma unroll
    for (int k = 0; k < PER; ++k) {
        int idx = base + k;
        if (idx < GBLK) blockOffs[idx] = run;
        run += v[k];
    }
    if (t == 1023) *dU = s[1023];
}

__global__ void compact_kernel(const u32* __restrict__ keys, const int* __restrict__ blockOffs,
                               u32* __restrict__ uniqKey, int* __restrict__ headPos,
                               const int* __restrict__ dU) {
    __shared__ int s[256];
    int tid = threadIdx.x;
    int i = blockIdx.x * 256 + tid;
    int h = 0;
    u32 key = 0u;
    if (i < N_SAMPLES) {
        key = keys[i];
        h = (i == 0) || (key != keys[i - 1]);
    }
    s[tid] = h;
    __syncthreads();
    for (int o = 1; o < 256; o <<= 1) {
        int x = (tid >= o) ? s[tid - o] : 0;
        __syncthreads();
        s[tid] += x;
        __syncthreads();
    }
    int excl = s[tid] - h;
    if (h) {
        int j = blockOffs[blockIdx.x] + excl;
        uniqKey[j] = key;
        headPos[j] = i;
    }
    if (i == 0) headPos[*dU] = N_SAMPLES;
}

// ---- fill: unpack 32-bit key to cols 0..31, zeros 32..47, counts int32 ----
__global__ void fill_kernel(const u32* __restrict__ uniqKey, const int* __restrict__ headPos,
                            const int* __restrict__ dU, int* __restrict__ out) {
    int j = blockIdx.x * 256 + threadIdx.x;
    if (j >= N_SAMPLES) return;
    int U = *dU;
    int4* bits = (int4*)out + (size_t)j * 12;
    int cnt = 0;
    if (j < U) {
        u32 k = uniqKey[j] ^ 0x80000000u;   // undo signed-order transform
#pragma unroll
        for (int q = 0; q < 8; ++q) {
            int c = q * 4;
            int4 v;
            v.x = (int)((k >> (c + 0)) & 1u);
            v.y = (int)((k >> (c + 1)) & 1u);
            v.z = (int)((k >> (c + 2)) & 1u);
            v.w = (int)((k >> (c + 3)) & 1u);
            bits[q] = v;
        }
        int4 z = make_int4(0, 0, 0, 0);
#pragma unroll
        for (int q = 8; q < 12; ++q) bits[q] = z;   // cols 32..47
        cnt = headPos[j + 1] - headPos[j];
    } else {
        int4 z = make_int4(0, 0, 0, 0);
#pragma unroll
        for (int q = 0; q < 12; ++q) bits[q] = z;
    }
    out[(size_t)N_SAMPLES * NBITS + j] = cnt;
}

extern "C" void kernel_launch(void* const* d_in, const int* in_sizes, int n_in,
                              void* d_out, int out_size, void* d_ws, size_t ws_size,
                              hipStream_t stream) {
    const float* theta = (const float*)d_in[0];
    const float* u = (const float*)d_in[1];
    int* out = (int*)d_out;
    char* ws = (char*)d_ws;

    u32* keysA = (u32*)(ws + 0);                 // 4,000,000 B
    u32* keysB = (u32*)(ws + 4000000);           // 4,000,000 B (later uniqKey)
    int* headPos = (int*)(ws + 8000000);         // 4,000,004 B
    int* g_hist = (int*)(ws + 12000064);         // 500,736 B
    int* g_off = (int*)(ws + 12600000);          // 500,736 B
    int* digitTotal = (int*)(ws + 13200000);     // 1 KB
    int* blockSums = (int*)(ws + 13210240);      // 15,628 B
    int* blockOffs = (int*)(ws + 13226624);      // 15,628 B
    int* dU = (int*)(ws + 13242880);             // 4 B

    // pass 0: pack + hist fused
    pack_hist0_kernel<<<NB, 256, 0, stream>>>(theta, u, keysA, g_hist);
    scan_digit_kernel<<<256, 512, 0, stream>>>(g_hist, g_off, digitTotal);
    scatter_kernel<<<NB, 512, 0, stream>>>(keysA, keysB, g_off, digitTotal, 0);

    u32* kin = keysB;
    u32* kout = keysA;
    for (int pass = 1; pass < 4; ++pass) {
        int shift = pass * 8;
        hist_kernel<<<NB, 256, 0, stream>>>(kin, shift, g_hist);
        scan_digit_kernel<<<256, 512, 0, stream>>>(g_hist, g_off, digitTotal);
        scatter_kernel<<<NB, 512, 0, stream>>>(kin, kout, g_off, digitTotal, shift);
        u32* t = kin; kin = kout; kout = t;
    }
    // 4 passes total -> sorted keys in keysA (kin == keysA), keysB free
    u32* uniqKey = keysB;

    head_reduce_kernel<<<GBLK, 256, 0, stream>>>(kin, blockSums);
    block_scan_kernel<<<1, 1024, 0, stream>>>(blockSums, blockOffs, dU);
    compact_kernel<<<GBLK, 256, 0, stream>>>(kin, blockOffs, uniqKey, headPos, dU);
    fill_kernel<<<GBLK, 256, 0, stream>>>(uniqKey, headPos, dU, out);
}